// Round 7
// baseline (246.197 us; speedup 1.0000x reference)
//
#include <hip/hip_runtime.h>

#define T_LEN 1500
#define TP    1536
#define EDIM  1280
#define NH    20
#define HD    64
#define KDIM  1280
#define NT    20          // K tiles of 64 (1280/64)

#define LOG2E 1.4426950408889634f

// ws layout (ushort elements). AO aliases X (X dead after QKV GEMM).
#define OFF_X    ((size_t)0)
#define OFF_AO   ((size_t)0)
#define OFF_W    ((size_t)7700480)    // 6016*1280
#define OFF_WO   ((size_t)12615680)   // +3840*1280
#define OFF_Q    ((size_t)14254080)   // +1280*1280
#define OFF_K    ((size_t)22118400)   // +80*1536*64
#define OFF_VT   ((size_t)29982720)   // +80*1536*64
// total: 37847040 u16 = 75.7 MB
// mask-nonzero flags (4*12*24 u32) live in d_out[0..1152).

typedef float  f32x4  __attribute__((ext_vector_type(4)));
typedef float  f32x16 __attribute__((ext_vector_type(16)));
typedef short  s16x8  __attribute__((ext_vector_type(8)));
typedef __bf16 bf16x8 __attribute__((ext_vector_type(8)));
typedef unsigned short u16;
typedef unsigned int   u32;
typedef unsigned int u32x4 __attribute__((ext_vector_type(4)));

__device__ __forceinline__ f32x4 mfma_bf16(s16x8 a, s16x8 b, f32x4 c) {
  return __builtin_amdgcn_mfma_f32_16x16x32_bf16(
      __builtin_bit_cast(bf16x8, a), __builtin_bit_cast(bf16x8, b), c, 0, 0, 0);
}

__device__ __forceinline__ f32x16 mfma32(s16x8 a, s16x8 b, f32x16 c) {
  return __builtin_amdgcn_mfma_f32_32x32x16_bf16(
      __builtin_bit_cast(bf16x8, a), __builtin_bit_cast(bf16x8, b), c, 0, 0, 0);
}

__device__ __forceinline__ u16 f2bf(float f) {
  union { float f; unsigned int u; } a; a.f = f;
  return (u16)((a.u + 0x7fffu + ((a.u >> 16) & 1u)) >> 16);
}

__device__ __forceinline__ float fexp2(float x) {
  return __builtin_amdgcn_exp2f(x);
}

__device__ __forceinline__ void gl_lds16(const u16* g, u16* l) {
  __builtin_amdgcn_global_load_lds(
      (const __attribute__((address_space(1))) unsigned int*)(const void*)g,
      (__attribute__((address_space(3))) unsigned int*)(void*)l, 16, 0, 0);
}

// GEMM-operand pre-swizzle (rule 21, both-sides): element (row, k) of any
// GEMM A/B operand is stored at k' = (k&~63) | (((k>>3)&7 ^ (row&7))<<3) | (k&7).
// gl_lds16 stages physical granules linearly; ds_read applies the same XOR.
// Applies to: X (prep), W (prep), Wo (prep), AO (attn epilogue writes).
// K storage swizzle (attn LDS): (t,d) at d' = ((d>>3 ^ (t&7))<<3)|(d&7)
// Vt storage swizzle (attn LDS): col t' = (t&~63)|(((t>>3)&7 ^ (d&7))<<3)|(t&7)

// ---------------------------------------------------------------- prep
__global__ __launch_bounds__(256) void prep_kernel(
    const float* __restrict__ x, const float* __restrict__ wq,
    const float* __restrict__ wk, const float* __restrict__ wv,
    const float* __restrict__ wo, const float* __restrict__ mask,
    u16* __restrict__ ws, u32* __restrict__ nzflags) {
  const int S0 = 1925120;          // X vec4 count (6016*1280/4)
  const int S1 = 1228800;          // Wqkv
  const int S2 = 409600;           // Wo
  const int P1 = 46080;            // one pad region (80*36*64/4)
  const int S3 = 2250000;          // mask scan vec4 count
  const int TOT = S0 + S1 + S2 + 3 * P1 + S3;
  for (int v = blockIdx.x * 256 + threadIdx.x; v < TOT; v += gridDim.x * 256) {
    if (v < S0) {
      int i = v * 4;
      int m = i / EDIM, e = i - m * EDIM;
      int ep = (e & ~63) | (((((e >> 3) & 7) ^ (m & 7))) << 3) | (e & 7);
      ushort4 o;
      if (m < 6000) {
        float4 f = *(const float4*)(x + i);
        o = make_ushort4(f2bf(f.x), f2bf(f.y), f2bf(f.z), f2bf(f.w));
      } else {
        o = make_ushort4(0, 0, 0, 0);
      }
      *(ushort4*)(ws + OFF_X + (size_t)m * EDIM + ep) = o;
    } else if (v < S0 + S1) {
      int j = (v - S0) * 4;
      int n = j / EDIM, e = j - n * EDIM;
      const float* s = (n < 1280) ? wq + (size_t)n * EDIM + e
                     : (n < 2560) ? wk + (size_t)(n - 1280) * EDIM + e
                                  : wv + (size_t)(n - 2560) * EDIM + e;
      float4 f = *(const float4*)s;
      int ep = (e & ~63) | (((((e >> 3) & 7) ^ (n & 7))) << 3) | (e & 7);
      *(ushort4*)(ws + OFF_W + (size_t)n * EDIM + ep) =
          make_ushort4(f2bf(f.x), f2bf(f.y), f2bf(f.z), f2bf(f.w));
    } else if (v < S0 + S1 + S2) {
      int j = (v - S0 - S1) * 4;
      int n = j / EDIM, e = j - n * EDIM;
      float4 f = *(const float4*)(wo + j);
      int ep = (e & ~63) | (((((e >> 3) & 7) ^ (n & 7))) << 3) | (e & 7);
      *(ushort4*)(ws + OFF_WO + (size_t)n * EDIM + ep) =
          make_ushort4(f2bf(f.x), f2bf(f.y), f2bf(f.z), f2bf(f.w));
    } else if (v < S0 + S1 + S2 + 3 * P1) {
      int p = v - (S0 + S1 + S2);
      ushort4 z = make_ushort4(0, 0, 0, 0);
      if (p < P1) {                       // Q pad rows t in [1500,1536)
        int p4 = p * 4; int bh = p4 / 2304; int rem = p4 - bh * 2304;
        int tt = rem >> 6, d = rem & 63;
        *(ushort4*)(ws + OFF_Q + ((size_t)(bh * TP + 1500 + tt)) * HD + d) = z;
      } else if (p < 2 * P1) {            // K pad rows (zero row: swizzle-invariant)
        int p4 = (p - P1) * 4; int bh = p4 / 2304; int rem = p4 - bh * 2304;
        int tt = rem >> 6, d = rem & 63;
        *(ushort4*)(ws + OFF_K + ((size_t)(bh * TP + 1500 + tt)) * HD + d) = z;
      } else {                            // Vt pad cols s in [1500,1536), swizzled
        int p4 = (p - 2 * P1) * 4; int bh = p4 / 2304; int rem = p4 - bh * 2304;
        int d = rem / 36, ss = rem - d * 36;
        int t = 1500 + ss;
        int tphys = (t & ~63) | (((((t >> 3) & 7) ^ (d & 7))) << 3) | (t & 7);
        *(ushort4*)(ws + OFF_VT + ((size_t)(bh * HD + d)) * TP + tphys) = z;
      }
    } else {                              // mask nonzero scan
      int p = v - (S0 + S1 + S2 + 3 * P1);
      int i4 = p * 4;
      int bb = i4 / 2250000;
      int rem = i4 - bb * 2250000;
      int q = rem / 1500;
      int s = rem - q * 1500;
      float4 f = *(const float4*)(mask + (size_t)bb * 2250000 + rem);
      if (f.x != 0.f || f.y != 0.f || f.z != 0.f || f.w != 0.f)
        atomicOr(&nzflags[(bb * 12 + (q >> 7)) * 24 + (s >> 6)], 1u);
    }
  }
}

// ------------------------------------------- 256x128 pipelined mainloop
// 8 waves (4m x 2n), BK=64, 3 LDS slots; register-pipelined fragment
// prefetch (reads issued one phase ahead, m201 pattern) so ds_read latency
// hides under the previous phase's 16-MFMA cluster; ONE barrier per K-tile
// (slot handoff), preceded by lgkmcnt(0) + counted vmcnt(6) (T3/T4);
// stage 2 K-tiles ahead; setprio around MFMA clusters (T5); granule-XOR
// swizzled LDS via pre-swizzled sources (T2, rule 21).
__device__ __forceinline__ void gemm_mainloop256(
    const u16* __restrict__ A, const u16* __restrict__ B,
    int mt, int nt, u16* lds, f32x4 acc[4][4]) {
  const int tid = threadIdx.x;           // 0..511
  const int lane = tid & 63, wid = tid >> 6;
  const int lg = lane >> 4, lr = lane & 15;
  const int wr = wid >> 1, wn = wid & 1;

  const u16* aB = A + (size_t)(mt * 256) * KDIM;
  const u16* bB = B + (size_t)(nt * 128) * KDIM;
  size_t aOff[4], bOff[2];
  #pragma unroll
  for (int l = 0; l < 4; ++l) {
    int gid = l * 512 + tid;            // A granule id 0..2047
    aOff[l] = (size_t)(gid >> 3) * KDIM + (gid & 7) * 8;
  }
  #pragma unroll
  for (int l = 0; l < 2; ++l) {
    int gid = l * 512 + tid;            // B granule id 0..1023
    bOff[l] = (size_t)(gid >> 3) * KDIM + (gid & 7) * 8;
  }
  const int ldsOff = tid * 8;
  int arow[4], brow[4];
  #pragma unroll
  for (int i = 0; i < 4; ++i) arow[i] = (wr * 64 + i * 16 + lr) * 64;
  #pragma unroll
  for (int j = 0; j < 4; ++j) brow[j] = (wn * 64 + j * 16 + lr) * 64;
  const int gsw0 = ((lg) ^ (lr & 7)) * 8;        // ks=0 phys granule
  const int gsw1 = ((4 + lg) ^ (lr & 7)) * 8;    // ks=1

  // prologue: stage tiles 0 (slot0) then 1 (slot1) — order matters for vmcnt
  #pragma unroll
  for (int t = 0; t < 2; ++t) {
    u16* dA = lds + t * 24576;
    u16* dB = dA + 16384;
    gl_lds16(aB + aOff[0] + t * 64, dA + ldsOff);
    gl_lds16(aB + aOff[1] + t * 64, dA + ldsOff + 4096);
    gl_lds16(bB + bOff[0] + t * 64, dB + ldsOff);
    gl_lds16(aB + aOff[2] + t * 64, dA + ldsOff + 8192);
    gl_lds16(aB + aOff[3] + t * 64, dA + ldsOff + 12288);
    gl_lds16(bB + bOff[1] + t * 64, dB + ldsOff + 4096);
  }
  // wait tile 0 only (6 of 12), then read its ks=0 fragments
  asm volatile("s_waitcnt vmcnt(6)" ::: "memory");
  __builtin_amdgcn_s_barrier();
  __builtin_amdgcn_sched_barrier(0);
  s16x8 ca[4], cb[4];
  #pragma unroll
  for (int i = 0; i < 4; ++i) ca[i] = *(const s16x8*)(lds + arow[i] + gsw0);
  #pragma unroll
  for (int j = 0; j < 4; ++j) cb[j] = *(const s16x8*)(lds + 16384 + brow[j] + gsw0);

  int s = 0;
  #pragma unroll 1
  for (int kt = 0; kt < NT; ++kt) {
    u16* cA = lds + s * 24576;
    u16* cB = cA + 16384;
    int ssl = s + 2; if (ssl >= 3) ssl -= 3;   // slot of tile kt-1 (released)
    u16* sA = lds + ssl * 24576;
    u16* sB = sA + 16384;
    const bool doStage = (kt + 2 < NT);
    // ---- P0: stage H0(kt+2) || prefetch Rnxt=(kt,ks1) || MFMA(Rcur) ----
    if (doStage) {
      gl_lds16(aB + aOff[0] + (kt + 2) * 64, sA + ldsOff);
      gl_lds16(aB + aOff[1] + (kt + 2) * 64, sA + ldsOff + 4096);
      gl_lds16(bB + bOff[0] + (kt + 2) * 64, sB + ldsOff);
    }
    s16x8 na[4], nb[4];
    #pragma unroll
    for (int i = 0; i < 4; ++i) na[i] = *(const s16x8*)(cA + arow[i] + gsw1);
    #pragma unroll
    for (int j = 0; j < 4; ++j) nb[j] = *(const s16x8*)(cB + brow[j] + gsw1);
    __builtin_amdgcn_s_setprio(1);
    #pragma unroll
    for (int i = 0; i < 4; ++i)
      #pragma unroll
      for (int j = 0; j < 4; ++j)
        acc[i][j] = mfma_bf16(ca[i], cb[j], acc[i][j]);
    __builtin_amdgcn_s_setprio(0);
    // ---- P1: stage H1(kt+2) || slot handoff || prefetch Rcur=(kt+1,ks0)
    //      || MFMA(Rnxt) ----
    if (doStage) {
      gl_lds16(aB + aOff[2] + (kt + 2) * 64, sA + ldsOff + 8192);
      gl_lds16(aB + aOff[3] + (kt + 2) * 64, sA + ldsOff + 12288);
      gl_lds16(bB + bOff[1] + (kt + 2) * 64, sB + ldsOff + 4096);
    }
    if (kt < NT - 1) {
      // lgkmcnt(0): this wave's reads from the slot being released are done
      asm volatile("s_waitcnt lgkmcnt(0)" ::: "memory");
      // counted vmcnt: tile kt+1's 6 loads (oldest) land; kt+2's in flight
      if (kt < NT - 2) asm volatile("s_waitcnt vmcnt(6)" ::: "memory");
      else             asm volatile("s_waitcnt vmcnt(0)" ::: "memory");
      __builtin_amdgcn_s_barrier();
      __builtin_amdgcn_sched_barrier(0);
      int sn = s + 1; if (sn >= 3) sn = 0;
      const u16* nA = lds + sn * 24576;
      const u16* nB2 = nA + 16384;
      #pragma unroll
      for (int i = 0; i < 4; ++i) ca[i] = *(const s16x8*)(nA + arow[i] + gsw0);
      #pragma unroll
      for (int j = 0; j < 4; ++j) cb[j] = *(const s16x8*)(nB2 + brow[j] + gsw0);
    }
    __builtin_amdgcn_s_setprio(1);
    #pragma unroll
    for (int i = 0; i < 4; ++i)
      #pragma unroll
      for (int j = 0; j < 4; ++j)
        acc[i][j] = mfma_bf16(na[i], nb[j], acc[i][j]);
    __builtin_amdgcn_s_setprio(0);
    s = s + 1; if (s >= 3) s = 0;
  }
}

// ------------------------------------------------------------ QKV GEMM
// grid: 720 = 8 XCDs x (3 mt x 30 nt); mt in [0,24) covers M=6144 (rows
// >= 6000 computed from in-bounds garbage, discarded).
__global__ __launch_bounds__(512) void gemm_qkv_kernel(
    const u16* __restrict__ X, const u16* __restrict__ W,
    const float* __restrict__ bq, const float* __restrict__ bv,
    u16* __restrict__ Qw, u16* __restrict__ Kw, u16* __restrict__ Vtw) {
  __shared__ __align__(16) u16 lds[3 * 24576];
  const int bid = blockIdx.x;
  const int xcd = bid & 7, idx = bid >> 3;
  const int mt = xcd * 3 + idx % 3;
  const int nt = idx / 3;
  f32x4 acc[4][4] = {};
  gemm_mainloop256(X, W, mt, nt, lds, acc);
  const int tid = threadIdx.x;
  const int lane = tid & 63, wid = tid >> 6;
  const int lg = lane >> 4, lr = lane & 15;
  const int wr = wid >> 1, wn = wid & 1;
  #pragma unroll
  for (int i = 0; i < 4; ++i) {
    #pragma unroll
    for (int r = 0; r < 4; ++r) {
      int mm = mt * 256 + wr * 64 + i * 16 + lg * 4 + r;
      if (mm >= 6000) continue;
      int bt = mm / 1500, tt = mm - bt * 1500;
      #pragma unroll
      for (int j = 0; j < 4; ++j) {
        int n = nt * 128 + wn * 64 + j * 16 + lr;
        float v = acc[i][j][r];
        if (n < 1280) {
          int hh = n >> 6, d = n & 63;
          Qw[((size_t)(bt * NH + hh) * TP + tt) * HD + d] =
              f2bf((v + bq[n]) * (0.125f * LOG2E));
        } else if (n < 2560) {
          int nn = n - 1280, hh = nn >> 6, d = nn & 63;
          int dp = ((((d >> 3) ^ (tt & 7))) << 3) | (d & 7);
          Kw[((size_t)(bt * NH + hh) * TP + tt) * HD + dp] = f2bf(v);
        } else {
          int nn = n - 2560, hh = nn >> 6, d = nn & 63;
          int tphys = (tt & ~63) | (((((tt >> 3) & 7) ^ (d & 7))) << 3) | (tt & 7);
          Vtw[((size_t)(bt * NH + hh) * HD + d) * TP + tphys] = f2bf(v + bv[nn]);
        }
      }
    }
  }
}

// ------------------------------------------------------------ attention
__global__ __launch_bounds__(256) void attn_kernel(
    const u16* __restrict__ Qw, const u16* __restrict__ Kw,
    const u16* __restrict__ Vtw, const float* __restrict__ mask,
    const u32* __restrict__ nzflags, u16* __restrict__ AO) {
  __shared__ __align__(16) u16 Kb[2][64 * 64];
  __shared__ __align__(16) u16 Vb[2][64 * 64];
  const int bhid = blockIdx.y;
  const int bb = bhid / NH, hh = bhid % NH;
  const int tid = threadIdx.x;
  const int w = tid >> 6;
  const int lane = tid & 63;
  const int lq = lane & 31;
  const int hi = lane >> 5;
  const int q0 = blockIdx.x * 128 + w * 32;
  const int qrow = q0 + lq;
  const int qm = qrow < (T_LEN - 1) ? qrow : (T_LEN - 1);
  const u16* Qp = Qw + (size_t)bhid * TP * HD;
  const u16* Kp = Kw + (size_t)bhid * TP * HD;
  const u16* Vp = Vtw + (size_t)bhid * HD * TP;
  const float* mp = mask + (size_t)bb * T_LEN * T_LEN + (size_t)qm * T_LEN;
  const u32* nzp = nzflags + (bb * 12 + blockIdx.x) * 24;

  s16x8 qf[4];
  #pragma unroll
  for (int c = 0; c < 4; ++c)
    qf[c] = *(const s16x8*)(Qp + (size_t)qrow * HD + c * 16 + hi * 8);

  f32x16 O0 = {}, O1 = {};
  float m = -3e38f, l = 0.f;

  {
    gl_lds16(Kp + tid * 8,                 Kb[0] + tid * 8);
    gl_lds16(Kp + 2048 + tid * 8,          Kb[0] + 2048 + tid * 8);
    int r = tid >> 3, g = tid & 7;
    gl_lds16(Vp + (size_t)r * TP + g * 8,          Vb[0] + tid * 8);
    gl_lds16(Vp + (size_t)(r + 32) * TP + g * 8,   Vb[0] + 2048 + tid * 8);
  }
  __syncthreads();

  int buf = 0;
  #pragma unroll 1
  for (int st = 0; st < 24; ++st) {
    const int s0 = st * 64;
    if (st < 23) {
      const int sn = s0 + 64;
      gl_lds16(Kp + (size_t)sn * HD + tid * 8,        Kb[buf ^ 1] + tid * 8);
      gl_lds16(Kp + (size_t)sn * HD + 2048 + tid * 8, Kb[buf ^ 1] + 2048 + tid * 8);
      int r = tid >> 3, g = tid & 7;
      gl_lds16(Vp + (size_t)r * TP + sn + g * 8,        Vb[buf ^ 1] + tid * 8);
      gl_lds16(Vp + (size_t)(r + 32) * TP + sn + g * 8, Vb[buf ^ 1] + 2048 + tid * 8);
    }
    const bool has_mask = nzp[st] != 0u;
    const u16* kb = Kb[buf];
    f32x16 S0a = {}, S1a = {};
    #pragma unroll
    for (int c = 0; c < 4; ++c) {
      int gc = 2 * c + hi;
      int gs = (gc ^ (lq & 7)) << 3;
      s16x8 k0 = *(const s16x8*)(kb + lq * 64 + gs);
      s16x8 k1 = *(const s16x8*)(kb + (32 + lq) * 64 + gs);
      S0a = mfma32(k0, qf[c], S0a);
      S1a = mfma32(k1, qf[c], S1a);
    }
    float p[32];
    #pragma unroll
    for (int r = 0; r < 16; ++r) { p[r] = S0a[r]; p[16 + r] = S1a[r]; }
    if (has_mask) {
      f32x4 mk[2][4];
      #pragma unroll
      for (int sh = 0; sh < 2; ++sh)
        #pragma unroll
        for (int g = 0; g < 4; ++g) {
          int sb = s0 + sh * 32 + 8 * g + 4 * hi;
          if (sb > T_LEN - 4) sb = T_LEN - 4;
          mk[sh][g] = *(const f32x4*)(mp + sb);
        }
      #pragma unroll
      for (int r = 0; r < 16; ++r) {
        p[r]      = fmaf(mk[0][r >> 2][r & 3], LOG2E, p[r]);
        p[16 + r] = fmaf(mk[1][r >> 2][r & 3], LOG2E, p[16 + r]);
      }
    }
    if (st == 23) {
      if (hi) { p[12] = p[13] = p[14] = p[15] = -1e30f; }
      #pragma unroll
      for (int r = 16; r < 32; ++r) p[r] = -1e30f;
    }
    float t1[16];
    #pragma unroll
    for (int r = 0; r < 16; ++r) t1[r] = fmaxf(p[r], p[r + 16]);
    #pragma unroll
    for (int r = 0; r < 8; ++r) t1[r] = fmaxf(t1[r], t1[r + 8]);
    float mx = fmaxf(fmaxf(fmaxf(t1[0], t1[1]), fmaxf(t1[2], t1[3])),
                     fmaxf(fmaxf(t1[4], t1[5]), fmaxf(t1[6], t1[7])));
    mx = fmaxf(mx, __shfl_xor(mx, 32));
    if (!__all(mx <= m + 8.f)) {
      float mn = fmaxf(m, mx);
      float sc = fexp2(m - mn);
      O0 *= sc; O1 *= sc; l *= sc;
      m = mn;
    }
    #pragma unroll
    for (int r = 0; r < 32; ++r) p[r] = fexp2(p[r] - m);
    float s1[16];
    #pragma unroll
    for (int r = 0; r < 16; ++r) s1[r] = p[r] + p[r + 16];
    #pragma unroll
    for (int r = 0; r < 8; ++r) s1[r] += s1[r + 8];
    #pragma unroll
    for (int r = 0; r < 4; ++r) s1[r] += s1[r + 4];
    float rs = (s1[0] + s1[1]) + (s1[2] + s1[3]);
    rs += __shfl_xor(rs, 32);
    l += rs;
    const u16* vb = Vb[buf];
    #pragma unroll
    for (int sh = 0; sh < 2; ++sh) {
      u32 pk[8];
      #pragma unroll
      for (int j = 0; j < 8; ++j)
        asm("v_cvt_pk_bf16_f32 %0, %1, %2"
            : "=v"(pk[j]) : "v"(p[sh * 16 + 2 * j]), "v"(p[sh * 16 + 2 * j + 1]));
      asm("v_permlane32_swap_b32 %0, %1" : "+v"(pk[0]), "+v"(pk[2]));
      asm("v_permlane32_swap_b32 %0, %1" : "+v"(pk[1]), "+v"(pk[3]));
      asm("v_permlane32_swap_b32 %0, %1" : "+v"(pk[4]), "+v"(pk[6]));
      asm("v_permlane32_swap_b32 %0, %1" : "+v"(pk[5]), "+v"(pk[7]));
      u32x4 ta = {pk[0], pk[1], pk[2], pk[3]};
      u32x4 tb = {pk[4], pk[5], pk[6], pk[7]};
      s16x8 pfa = __builtin_bit_cast(s16x8, ta);
      s16x8 pfb = __builtin_bit_cast(s16x8, tb);
      int ga = sh * 4 + hi, gb = sh * 4 + 2 + hi;
      {
        int d = lq;
        s16x8 va = *(const s16x8*)(vb + d * 64 + ((ga ^ (d & 7)) << 3));
        s16x8 vc = *(const s16x8*)(vb + d * 64 + ((gb ^ (d & 7)) << 3));
        O0 = mfma32(va, pfa, O0);
        O0 = mfma32(vc, pfb, O0);
      }
      {
        int d = 32 + lq;
        s16x8 va = *(const s16x8*)(vb + d * 64 + ((ga ^ (d & 7)) << 3));
        s16x8 vc = *(const s16x8*)(vb + d * 64 + ((gb ^ (d & 7)) << 3));
        O1 = mfma32(va, pfa, O1);
        O1 = mfma32(vc, pfb, O1);
      }
    }
    __syncthreads();
    buf ^= 1;
  }

  if (qrow < T_LEN) {
    float inv = 1.f / l;
    int arow = bb * T_LEN + qrow;
    int key = arow & 7;                  // AO pre-swizzle for gemm_out (rule 21)
    size_t base = (size_t)arow * EDIM + hh * 64;
    #pragma unroll
    for (int g = 0; g < 4; ++g) {
      ushort4 o0, o1;
      o0.x = f2bf(O0[4 * g + 0] * inv); o0.y = f2bf(O0[4 * g + 1] * inv);
      o0.z = f2bf(O0[4 * g + 2] * inv); o0.w = f2bf(O0[4 * g + 3] * inv);
      o1.x = f2bf(O1[4 * g + 0] * inv); o1.y = f2bf(O1[4 * g + 1] * inv);
      o1.z = f2bf(O1[4 * g + 2] * inv); o1.w = f2bf(O1[4 * g + 3] * inv);
      *(ushort4*)(AO + base + ((g ^ key) << 3) + 4 * hi)       = o0;
      *(ushort4*)(AO + base + (((4 + g) ^ key) << 3) + 4 * hi) = o1;
    }
  }
}

// --------------------------------------------------------- output GEMM
// grid: 240 = 8 XCDs x (3 mt x 10 nt).
__global__ __launch_bounds__(512) void gemm_out_kernel(
    const u16* __restrict__ AOb, const u16* __restrict__ Wob,
    const float* __restrict__ bo, float* __restrict__ out) {
  __shared__ __align__(16) u16 lds[3 * 24576];
  const int bid = blockIdx.x;
  const int xcd = bid & 7, idx = bid >> 3;
  const int mt = xcd * 3 + idx % 3;
  const int nt = idx / 3;
  f32x4 acc[4][4] = {};
  gemm_mainloop256(AOb, Wob, mt, nt, lds, acc);
  const int tid = threadIdx.x;
  const int lane = tid & 63, wid = tid >> 6;
  const int lg = lane >> 4, lr = lane & 15;
  const int wr = wid >> 1, wn = wid & 1;
  #pragma unroll
  for (int i = 0; i < 4; ++i) {
    #pragma unroll
    for (int r = 0; r < 4; ++r) {
      int mm = mt * 256 + wr * 64 + i * 16 + lg * 4 + r;
      if (mm >= 6000) continue;
      #pragma unroll
      for (int j = 0; j < 4; ++j) {
        int n = nt * 128 + wn * 64 + j * 16 + lr;
        out[(size_t)mm * EDIM + n] = acc[i][j][r] + bo[n];
      }
    }
  }
}

// ---------------------------------------------------------------- launch
extern "C" void kernel_launch(void* const* d_in, const int* in_sizes, int n_in,
                              void* d_out, int out_size, void* d_ws, size_t ws_size,
                              hipStream_t stream) {
  const float* x    = (const float*)d_in[0];
  const float* mask = (const float*)d_in[1];
  const float* wq   = (const float*)d_in[2];
  const float* bq   = (const float*)d_in[3];
  const float* wk   = (const float*)d_in[4];
  const float* wv   = (const float*)d_in[5];
  const float* bv   = (const float*)d_in[6];
  const float* wo   = (const float*)d_in[7];
  const float* bo   = (const float*)d_in[8];
  float* out = (float*)d_out;
  u16* ws = (u16*)d_ws;
  u32* nzflags = (u32*)d_out;   // 1152 u32; overwritten by gemm_out later

  hipMemsetAsync(nzflags, 0, 1152 * sizeof(u32), stream);
  prep_kernel<<<2048, 256, 0, stream>>>(x, wq, wk, wv, wo, mask, ws, nzflags);
  gemm_qkv_kernel<<<720, 512, 0, stream>>>(
      ws + OFF_X, ws + OFF_W, bq, bv, ws + OFF_Q, ws + OFF_K, ws + OFF_VT);
  attn_kernel<<<dim3(12, 80), 256, 0, stream>>>(
      ws + OFF_Q, ws + OFF_K, ws + OFF_VT, mask, nzflags, ws + OFF_AO);
  gemm_out_kernel<<<240, 512, 0, stream>>>(
      ws + OFF_AO, ws + OFF_WO, bo, out);
}

// Round 8
// 245.699 us; speedup vs baseline: 1.0020x; 1.0020x over previous
//
#include <hip/hip_runtime.h>

#define T_LEN 1500
#define TP    1536
#define EDIM  1280
#define NH    20
#define HD    64
#define KDIM  1280
#define NT    20          // K tiles of 64 (1280/64)

#define LOG2E 1.4426950408889634f

// ws layout (ushort elements). AO aliases X (X dead after QKV GEMM).
#define OFF_X    ((size_t)0)
#define OFF_AO   ((size_t)0)
#define OFF_W    ((size_t)7700480)    // 6016*1280
#define OFF_WO   ((size_t)12615680)   // +3840*1280
#define OFF_Q    ((size_t)14254080)   // +1280*1280
#define OFF_K    ((size_t)22118400)   // +80*1536*64
#define OFF_VT   ((size_t)29982720)   // +80*1536*64
// total: 37847040 u16 = 75.7 MB
// mask-nonzero flags (4*12*24 u32) live in d_out[0..1152).

typedef float  f32x4  __attribute__((ext_vector_type(4)));
typedef float  f32x16 __attribute__((ext_vector_type(16)));
typedef short  s16x8  __attribute__((ext_vector_type(8)));
typedef __bf16 bf16x8 __attribute__((ext_vector_type(8)));
typedef unsigned short u16;
typedef unsigned int   u32;
typedef unsigned int u32x4 __attribute__((ext_vector_type(4)));

__device__ __forceinline__ f32x4 mfma_bf16(s16x8 a, s16x8 b, f32x4 c) {
  return __builtin_amdgcn_mfma_f32_16x16x32_bf16(
      __builtin_bit_cast(bf16x8, a), __builtin_bit_cast(bf16x8, b), c, 0, 0, 0);
}

__device__ __forceinline__ f32x16 mfma32(s16x8 a, s16x8 b, f32x16 c) {
  return __builtin_amdgcn_mfma_f32_32x32x16_bf16(
      __builtin_bit_cast(bf16x8, a), __builtin_bit_cast(bf16x8, b), c, 0, 0, 0);
}

__device__ __forceinline__ u16 f2bf(float f) {
  union { float f; unsigned int u; } a; a.f = f;
  return (u16)((a.u + 0x7fffu + ((a.u >> 16) & 1u)) >> 16);
}

__device__ __forceinline__ float fexp2(float x) {
  return __builtin_amdgcn_exp2f(x);
}

__device__ __forceinline__ void gl_lds16(const u16* g, u16* l) {
  __builtin_amdgcn_global_load_lds(
      (const __attribute__((address_space(1))) unsigned int*)(const void*)g,
      (__attribute__((address_space(3))) unsigned int*)(void*)l, 16, 0, 0);
}

// GEMM-operand pre-swizzle (rule 21, both-sides): element (row, k) of any
// GEMM A/B operand is stored at k' = (k&~63) | (((k>>3)&7 ^ (row&7))<<3) | (k&7).
// gl_lds16 stages physical granules linearly; ds_read applies the same XOR.
// Applies to: X (prep), W (prep), Wo (prep), AO (attn epilogue writes).
// K storage swizzle (attn LDS): (t,d) at d' = ((d>>3 ^ (t&7))<<3)|(d&7)
// Vt storage swizzle (attn LDS): col t' = (t&~63)|(((t>>3)&7 ^ (d&7))<<3)|(t&7)

// ---------------------------------------------------------------- prep
__global__ __launch_bounds__(256) void prep_kernel(
    const float* __restrict__ x, const float* __restrict__ wq,
    const float* __restrict__ wk, const float* __restrict__ wv,
    const float* __restrict__ wo, const float* __restrict__ mask,
    u16* __restrict__ ws, u32* __restrict__ nzflags) {
  const int S0 = 1925120;          // X vec4 count (6016*1280/4)
  const int S1 = 1228800;          // Wqkv
  const int S2 = 409600;           // Wo
  const int P1 = 46080;            // one pad region (80*36*64/4)
  const int S3 = 2250000;          // mask scan vec4 count
  const int TOT = S0 + S1 + S2 + 3 * P1 + S3;
  for (int v = blockIdx.x * 256 + threadIdx.x; v < TOT; v += gridDim.x * 256) {
    if (v < S0) {
      int i = v * 4;
      int m = i / EDIM, e = i - m * EDIM;
      int ep = (e & ~63) | (((((e >> 3) & 7) ^ (m & 7))) << 3) | (e & 7);
      ushort4 o;
      if (m < 6000) {
        float4 f = *(const float4*)(x + i);
        o = make_ushort4(f2bf(f.x), f2bf(f.y), f2bf(f.z), f2bf(f.w));
      } else {
        o = make_ushort4(0, 0, 0, 0);
      }
      *(ushort4*)(ws + OFF_X + (size_t)m * EDIM + ep) = o;
    } else if (v < S0 + S1) {
      int j = (v - S0) * 4;
      int n = j / EDIM, e = j - n * EDIM;
      const float* s = (n < 1280) ? wq + (size_t)n * EDIM + e
                     : (n < 2560) ? wk + (size_t)(n - 1280) * EDIM + e
                                  : wv + (size_t)(n - 2560) * EDIM + e;
      float4 f = *(const float4*)s;
      int ep = (e & ~63) | (((((e >> 3) & 7) ^ (n & 7))) << 3) | (e & 7);
      *(ushort4*)(ws + OFF_W + (size_t)n * EDIM + ep) =
          make_ushort4(f2bf(f.x), f2bf(f.y), f2bf(f.z), f2bf(f.w));
    } else if (v < S0 + S1 + S2) {
      int j = (v - S0 - S1) * 4;
      int n = j / EDIM, e = j - n * EDIM;
      float4 f = *(const float4*)(wo + j);
      int ep = (e & ~63) | (((((e >> 3) & 7) ^ (n & 7))) << 3) | (e & 7);
      *(ushort4*)(ws + OFF_WO + (size_t)n * EDIM + ep) =
          make_ushort4(f2bf(f.x), f2bf(f.y), f2bf(f.z), f2bf(f.w));
    } else if (v < S0 + S1 + S2 + 3 * P1) {
      int p = v - (S0 + S1 + S2);
      ushort4 z = make_ushort4(0, 0, 0, 0);
      if (p < P1) {                       // Q pad rows t in [1500,1536)
        int p4 = p * 4; int bh = p4 / 2304; int rem = p4 - bh * 2304;
        int tt = rem >> 6, d = rem & 63;
        *(ushort4*)(ws + OFF_Q + ((size_t)(bh * TP + 1500 + tt)) * HD + d) = z;
      } else if (p < 2 * P1) {            // K pad rows (zero row: swizzle-invariant)
        int p4 = (p - P1) * 4; int bh = p4 / 2304; int rem = p4 - bh * 2304;
        int tt = rem >> 6, d = rem & 63;
        *(ushort4*)(ws + OFF_K + ((size_t)(bh * TP + 1500 + tt)) * HD + d) = z;
      } else {                            // Vt pad cols s in [1500,1536), swizzled
        int p4 = (p - 2 * P1) * 4; int bh = p4 / 2304; int rem = p4 - bh * 2304;
        int d = rem / 36, ss = rem - d * 36;
        int t = 1500 + ss;
        int tphys = (t & ~63) | (((((t >> 3) & 7) ^ (d & 7))) << 3) | (t & 7);
        *(ushort4*)(ws + OFF_VT + ((size_t)(bh * HD + d)) * TP + tphys) = z;
      }
    } else {                              // mask nonzero scan
      int p = v - (S0 + S1 + S2 + 3 * P1);
      int i4 = p * 4;
      int bb = i4 / 2250000;
      int rem = i4 - bb * 2250000;
      int q = rem / 1500;
      int s = rem - q * 1500;
      float4 f = *(const float4*)(mask + (size_t)bb * 2250000 + rem);
      if (f.x != 0.f || f.y != 0.f || f.z != 0.f || f.w != 0.f)
        atomicOr(&nzflags[(bb * 12 + (q >> 7)) * 24 + (s >> 6)], 1u);
    }
  }
}

// ------------------------------------------- 256x128 pipelined mainloop
// 8 waves (4m x 2n), BK=64, 3 LDS slots; register-pipelined fragment
// prefetch (reads issued one phase ahead, m201 pattern) so ds_read latency
// hides under the previous phase's 16-MFMA cluster; ONE barrier per K-tile
// (slot handoff), preceded by lgkmcnt(0) + counted vmcnt(6) (T3/T4);
// stage 2 K-tiles ahead; setprio around MFMA clusters (T5); granule-XOR
// swizzled LDS via pre-swizzled sources (T2, rule 21).
__device__ __forceinline__ void gemm_mainloop256(
    const u16* __restrict__ A, const u16* __restrict__ B,
    int mt, int nt, u16* lds, f32x4 acc[4][4]) {
  const int tid = threadIdx.x;           // 0..511
  const int lane = tid & 63, wid = tid >> 6;
  const int lg = lane >> 4, lr = lane & 15;
  const int wr = wid >> 1, wn = wid & 1;

  const u16* aB = A + (size_t)(mt * 256) * KDIM;
  const u16* bB = B + (size_t)(nt * 128) * KDIM;
  size_t aOff[4], bOff[2];
  #pragma unroll
  for (int l = 0; l < 4; ++l) {
    int gid = l * 512 + tid;            // A granule id 0..2047
    aOff[l] = (size_t)(gid >> 3) * KDIM + (gid & 7) * 8;
  }
  #pragma unroll
  for (int l = 0; l < 2; ++l) {
    int gid = l * 512 + tid;            // B granule id 0..1023
    bOff[l] = (size_t)(gid >> 3) * KDIM + (gid & 7) * 8;
  }
  const int ldsOff = tid * 8;
  int arow[4], brow[4];
  #pragma unroll
  for (int i = 0; i < 4; ++i) arow[i] = (wr * 64 + i * 16 + lr) * 64;
  #pragma unroll
  for (int j = 0; j < 4; ++j) brow[j] = (wn * 64 + j * 16 + lr) * 64;
  const int gsw0 = ((lg) ^ (lr & 7)) * 8;        // ks=0 phys granule
  const int gsw1 = ((4 + lg) ^ (lr & 7)) * 8;    // ks=1

  // prologue: stage tiles 0 (slot0) then 1 (slot1) — order matters for vmcnt
  #pragma unroll
  for (int t = 0; t < 2; ++t) {
    u16* dA = lds + t * 24576;
    u16* dB = dA + 16384;
    gl_lds16(aB + aOff[0] + t * 64, dA + ldsOff);
    gl_lds16(aB + aOff[1] + t * 64, dA + ldsOff + 4096);
    gl_lds16(bB + bOff[0] + t * 64, dB + ldsOff);
    gl_lds16(aB + aOff[2] + t * 64, dA + ldsOff + 8192);
    gl_lds16(aB + aOff[3] + t * 64, dA + ldsOff + 12288);
    gl_lds16(bB + bOff[1] + t * 64, dB + ldsOff + 4096);
  }
  // wait tile 0 only (6 of 12), then read its ks=0 fragments
  asm volatile("s_waitcnt vmcnt(6)" ::: "memory");
  __builtin_amdgcn_s_barrier();
  __builtin_amdgcn_sched_barrier(0);
  s16x8 ca[4], cb[4];
  #pragma unroll
  for (int i = 0; i < 4; ++i) ca[i] = *(const s16x8*)(lds + arow[i] + gsw0);
  #pragma unroll
  for (int j = 0; j < 4; ++j) cb[j] = *(const s16x8*)(lds + 16384 + brow[j] + gsw0);

  int s = 0;
  #pragma unroll 1
  for (int kt = 0; kt < NT; ++kt) {
    u16* cA = lds + s * 24576;
    u16* cB = cA + 16384;
    int ssl = s + 2; if (ssl >= 3) ssl -= 3;   // slot of tile kt-1 (released)
    u16* sA = lds + ssl * 24576;
    u16* sB = sA + 16384;
    const bool doStage = (kt + 2 < NT);
    // ---- P0: stage H0(kt+2) || prefetch Rnxt=(kt,ks1) || MFMA(Rcur) ----
    if (doStage) {
      gl_lds16(aB + aOff[0] + (kt + 2) * 64, sA + ldsOff);
      gl_lds16(aB + aOff[1] + (kt + 2) * 64, sA + ldsOff + 4096);
      gl_lds16(bB + bOff[0] + (kt + 2) * 64, sB + ldsOff);
    }
    s16x8 na[4], nb[4];
    #pragma unroll
    for (int i = 0; i < 4; ++i) na[i] = *(const s16x8*)(cA + arow[i] + gsw1);
    #pragma unroll
    for (int j = 0; j < 4; ++j) nb[j] = *(const s16x8*)(cB + brow[j] + gsw1);
    __builtin_amdgcn_s_setprio(1);
    #pragma unroll
    for (int i = 0; i < 4; ++i)
      #pragma unroll
      for (int j = 0; j < 4; ++j)
        acc[i][j] = mfma_bf16(ca[i], cb[j], acc[i][j]);
    __builtin_amdgcn_s_setprio(0);
    // ---- P1: stage H1(kt+2) || slot handoff || prefetch Rcur=(kt+1,ks0)
    //      || MFMA(Rnxt) ----
    if (doStage) {
      gl_lds16(aB + aOff[2] + (kt + 2) * 64, sA + ldsOff + 8192);
      gl_lds16(aB + aOff[3] + (kt + 2) * 64, sA + ldsOff + 12288);
      gl_lds16(bB + bOff[1] + (kt + 2) * 64, sB + ldsOff + 4096);
    }
    if (kt < NT - 1) {
      // lgkmcnt(0): this wave's reads from the slot being released are done
      asm volatile("s_waitcnt lgkmcnt(0)" ::: "memory");
      // counted vmcnt: tile kt+1's 6 loads (oldest) land; kt+2's in flight
      if (kt < NT - 2) asm volatile("s_waitcnt vmcnt(6)" ::: "memory");
      else             asm volatile("s_waitcnt vmcnt(0)" ::: "memory");
      __builtin_amdgcn_s_barrier();
      __builtin_amdgcn_sched_barrier(0);
      int sn = s + 1; if (sn >= 3) sn = 0;
      const u16* nA = lds + sn * 24576;
      const u16* nB2 = nA + 16384;
      #pragma unroll
      for (int i = 0; i < 4; ++i) ca[i] = *(const s16x8*)(nA + arow[i] + gsw0);
      #pragma unroll
      for (int j = 0; j < 4; ++j) cb[j] = *(const s16x8*)(nB2 + brow[j] + gsw0);
    }
    __builtin_amdgcn_s_setprio(1);
    #pragma unroll
    for (int i = 0; i < 4; ++i)
      #pragma unroll
      for (int j = 0; j < 4; ++j)
        acc[i][j] = mfma_bf16(na[i], nb[j], acc[i][j]);
    __builtin_amdgcn_s_setprio(0);
    s = s + 1; if (s >= 3) s = 0;
  }
}

// ------------------------------------------------------------ QKV GEMM
// grid: 720 = 8 XCDs x (3 mt x 30 nt); mt in [0,24) covers M=6144 (rows
// >= 6000 computed from in-bounds garbage, discarded).
__global__ __launch_bounds__(512) void gemm_qkv_kernel(
    const u16* __restrict__ X, const u16* __restrict__ W,
    const float* __restrict__ bq, const float* __restrict__ bv,
    u16* __restrict__ Qw, u16* __restrict__ Kw, u16* __restrict__ Vtw) {
  __shared__ __align__(16) u16 lds[3 * 24576];
  const int bid = blockIdx.x;
  const int xcd = bid & 7, idx = bid >> 3;
  const int mt = xcd * 3 + idx % 3;
  const int nt = idx / 3;
  f32x4 acc[4][4] = {};
  gemm_mainloop256(X, W, mt, nt, lds, acc);
  const int tid = threadIdx.x;
  const int lane = tid & 63, wid = tid >> 6;
  const int lg = lane >> 4, lr = lane & 15;
  const int wr = wid >> 1, wn = wid & 1;
  #pragma unroll
  for (int i = 0; i < 4; ++i) {
    #pragma unroll
    for (int r = 0; r < 4; ++r) {
      int mm = mt * 256 + wr * 64 + i * 16 + lg * 4 + r;
      if (mm >= 6000) continue;
      int bt = mm / 1500, tt = mm - bt * 1500;
      #pragma unroll
      for (int j = 0; j < 4; ++j) {
        int n = nt * 128 + wn * 64 + j * 16 + lr;
        float v = acc[i][j][r];
        if (n < 1280) {
          int hh = n >> 6, d = n & 63;
          Qw[((size_t)(bt * NH + hh) * TP + tt) * HD + d] =
              f2bf((v + bq[n]) * (0.125f * LOG2E));
        } else if (n < 2560) {
          int nn = n - 1280, hh = nn >> 6, d = nn & 63;
          int dp = ((((d >> 3) ^ (tt & 7))) << 3) | (d & 7);
          Kw[((size_t)(bt * NH + hh) * TP + tt) * HD + dp] = f2bf(v);
        } else {
          int nn = n - 2560, hh = nn >> 6, d = nn & 63;
          int tphys = (tt & ~63) | (((((tt >> 3) & 7) ^ (d & 7))) << 3) | (tt & 7);
          Vtw[((size_t)(bt * NH + hh) * HD + d) * TP + tphys] = f2bf(v + bv[nn]);
        }
      }
    }
  }
}

// ------------------------------------------------------------ attention
__global__ __launch_bounds__(256) void attn_kernel(
    const u16* __restrict__ Qw, const u16* __restrict__ Kw,
    const u16* __restrict__ Vtw, const float* __restrict__ mask,
    const u32* __restrict__ nzflags, u16* __restrict__ AO) {
  __shared__ __align__(16) u16 Kb[2][64 * 64];
  __shared__ __align__(16) u16 Vb[2][64 * 64];
  const int bhid = blockIdx.y;
  const int bb = bhid / NH, hh = bhid % NH;
  const int tid = threadIdx.x;
  const int w = tid >> 6;
  const int lane = tid & 63;
  const int lq = lane & 31;
  const int hi = lane >> 5;
  const int q0 = blockIdx.x * 128 + w * 32;
  const int qrow = q0 + lq;
  const int qm = qrow < (T_LEN - 1) ? qrow : (T_LEN - 1);
  const u16* Qp = Qw + (size_t)bhid * TP * HD;
  const u16* Kp = Kw + (size_t)bhid * TP * HD;
  const u16* Vp = Vtw + (size_t)bhid * HD * TP;
  const float* mp = mask + (size_t)bb * T_LEN * T_LEN + (size_t)qm * T_LEN;
  const u32* nzp = nzflags + (bb * 12 + blockIdx.x) * 24;

  s16x8 qf[4];
  #pragma unroll
  for (int c = 0; c < 4; ++c)
    qf[c] = *(const s16x8*)(Qp + (size_t)qrow * HD + c * 16 + hi * 8);

  f32x16 O0 = {}, O1 = {};
  float m = -3e38f, l = 0.f;

  {
    gl_lds16(Kp + tid * 8,                 Kb[0] + tid * 8);
    gl_lds16(Kp + 2048 + tid * 8,          Kb[0] + 2048 + tid * 8);
    int r = tid >> 3, g = tid & 7;
    gl_lds16(Vp + (size_t)r * TP + g * 8,          Vb[0] + tid * 8);
    gl_lds16(Vp + (size_t)(r + 32) * TP + g * 8,   Vb[0] + 2048 + tid * 8);
  }
  __syncthreads();

  int buf = 0;
  #pragma unroll 1
  for (int st = 0; st < 24; ++st) {
    const int s0 = st * 64;
    if (st < 23) {
      const int sn = s0 + 64;
      gl_lds16(Kp + (size_t)sn * HD + tid * 8,        Kb[buf ^ 1] + tid * 8);
      gl_lds16(Kp + (size_t)sn * HD + 2048 + tid * 8, Kb[buf ^ 1] + 2048 + tid * 8);
      int r = tid >> 3, g = tid & 7;
      gl_lds16(Vp + (size_t)r * TP + sn + g * 8,        Vb[buf ^ 1] + tid * 8);
      gl_lds16(Vp + (size_t)(r + 32) * TP + sn + g * 8, Vb[buf ^ 1] + 2048 + tid * 8);
    }
    const bool has_mask = nzp[st] != 0u;
    const u16* kb = Kb[buf];
    f32x16 S0a = {}, S1a = {};
    #pragma unroll
    for (int c = 0; c < 4; ++c) {
      int gc = 2 * c + hi;
      int gs = (gc ^ (lq & 7)) << 3;
      s16x8 k0 = *(const s16x8*)(kb + lq * 64 + gs);
      s16x8 k1 = *(const s16x8*)(kb + (32 + lq) * 64 + gs);
      S0a = mfma32(k0, qf[c], S0a);
      S1a = mfma32(k1, qf[c], S1a);
    }
    float p[32];
    #pragma unroll
    for (int r = 0; r < 16; ++r) { p[r] = S0a[r]; p[16 + r] = S1a[r]; }
    if (has_mask) {
      f32x4 mk[2][4];
      #pragma unroll
      for (int sh = 0; sh < 2; ++sh)
        #pragma unroll
        for (int g = 0; g < 4; ++g) {
          int sb = s0 + sh * 32 + 8 * g + 4 * hi;
          if (sb > T_LEN - 4) sb = T_LEN - 4;
          mk[sh][g] = *(const f32x4*)(mp + sb);
        }
      #pragma unroll
      for (int r = 0; r < 16; ++r) {
        p[r]      = fmaf(mk[0][r >> 2][r & 3], LOG2E, p[r]);
        p[16 + r] = fmaf(mk[1][r >> 2][r & 3], LOG2E, p[16 + r]);
      }
    }
    if (st == 23) {
      if (hi) { p[12] = p[13] = p[14] = p[15] = -1e30f; }
      #pragma unroll
      for (int r = 16; r < 32; ++r) p[r] = -1e30f;
    }
    float t1[16];
    #pragma unroll
    for (int r = 0; r < 16; ++r) t1[r] = fmaxf(p[r], p[r + 16]);
    #pragma unroll
    for (int r = 0; r < 8; ++r) t1[r] = fmaxf(t1[r], t1[r + 8]);
    float mx = fmaxf(fmaxf(fmaxf(t1[0], t1[1]), fmaxf(t1[2], t1[3])),
                     fmaxf(fmaxf(t1[4], t1[5]), fmaxf(t1[6], t1[7])));
    mx = fmaxf(mx, __shfl_xor(mx, 32));
    if (!__all(mx <= m + 8.f)) {
      float mn = fmaxf(m, mx);
      float sc = fexp2(m - mn);
      O0 *= sc; O1 *= sc; l *= sc;
      m = mn;
    }
    #pragma unroll
    for (int r = 0; r < 32; ++r) p[r] = fexp2(p[r] - m);
    float s1[16];
    #pragma unroll
    for (int r = 0; r < 16; ++r) s1[r] = p[r] + p[r + 16];
    #pragma unroll
    for (int r = 0; r < 8; ++r) s1[r] += s1[r + 8];
    #pragma unroll
    for (int r = 0; r < 4; ++r) s1[r] += s1[r + 4];
    float rs = (s1[0] + s1[1]) + (s1[2] + s1[3]);
    rs += __shfl_xor(rs, 32);
    l += rs;
    const u16* vb = Vb[buf];
    #pragma unroll
    for (int sh = 0; sh < 2; ++sh) {
      u32 pk[8];
      #pragma unroll
      for (int j = 0; j < 8; ++j)
        asm("v_cvt_pk_bf16_f32 %0, %1, %2"
            : "=v"(pk[j]) : "v"(p[sh * 16 + 2 * j]), "v"(p[sh * 16 + 2 * j + 1]));
      asm("v_permlane32_swap_b32 %0, %1" : "+v"(pk[0]), "+v"(pk[2]));
      asm("v_permlane32_swap_b32 %0, %1" : "+v"(pk[1]), "+v"(pk[3]));
      asm("v_permlane32_swap_b32 %0, %1" : "+v"(pk[4]), "+v"(pk[6]));
      asm("v_permlane32_swap_b32 %0, %1" : "+v"(pk[5]), "+v"(pk[7]));
      u32x4 ta = {pk[0], pk[1], pk[2], pk[3]};
      u32x4 tb = {pk[4], pk[5], pk[6], pk[7]};
      s16x8 pfa = __builtin_bit_cast(s16x8, ta);
      s16x8 pfb = __builtin_bit_cast(s16x8, tb);
      int ga = sh * 4 + hi, gb = sh * 4 + 2 + hi;
      {
        int d = lq;
        s16x8 va = *(const s16x8*)(vb + d * 64 + ((ga ^ (d & 7)) << 3));
        s16x8 vc = *(const s16x8*)(vb + d * 64 + ((gb ^ (d & 7)) << 3));
        O0 = mfma32(va, pfa, O0);
        O0 = mfma32(vc, pfb, O0);
      }
      {
        int d = 32 + lq;
        s16x8 va = *(const s16x8*)(vb + d * 64 + ((ga ^ (d & 7)) << 3));
        s16x8 vc = *(const s16x8*)(vb + d * 64 + ((gb ^ (d & 7)) << 3));
        O1 = mfma32(va, pfa, O1);
        O1 = mfma32(vc, pfb, O1);
      }
    }
    __syncthreads();
    buf ^= 1;
  }

  if (qrow < T_LEN) {
    float inv = 1.f / l;
    int arow = bb * T_LEN + qrow;
    int key = arow & 7;                  // AO pre-swizzle for gemm_out (rule 21)
    size_t base = (size_t)arow * EDIM + hh * 64;
    #pragma unroll
    for (int g = 0; g < 4; ++g) {
      ushort4 o0, o1;
      o0.x = f2bf(O0[4 * g + 0] * inv); o0.y = f2bf(O0[4 * g + 1] * inv);
      o0.z = f2bf(O0[4 * g + 2] * inv); o0.w = f2bf(O0[4 * g + 3] * inv);
      o1.x = f2bf(O1[4 * g + 0] * inv); o1.y = f2bf(O1[4 * g + 1] * inv);
      o1.z = f2bf(O1[4 * g + 2] * inv); o1.w = f2bf(O1[4 * g + 3] * inv);
      *(ushort4*)(AO + base + ((g ^ key) << 3) + 4 * hi)       = o0;
      *(ushort4*)(AO + base + (((4 + g) ^ key) << 3) + 4 * hi) = o1;
    }
  }
}

// --------------------------------------------------------- output GEMM
// grid: 240 = 8 XCDs x (3 mt x 10 nt).
__global__ __launch_bounds__(512) void gemm_out_kernel(
    const u16* __restrict__ AOb, const u16* __restrict__ Wob,
    const float* __restrict__ bo, float* __restrict__ out) {
  __shared__ __align__(16) u16 lds[3 * 24576];
  const int bid = blockIdx.x;
  const int xcd = bid & 7, idx = bid >> 3;
  const int mt = xcd * 3 + idx % 3;
  const int nt = idx / 3;
  f32x4 acc[4][4] = {};
  gemm_mainloop256(AOb, Wob, mt, nt, lds, acc);
  const int tid = threadIdx.x;
  const int lane = tid & 63, wid = tid >> 6;
  const int lg = lane >> 4, lr = lane & 15;
  const int wr = wid >> 1, wn = wid & 1;
  #pragma unroll
  for (int i = 0; i < 4; ++i) {
    #pragma unroll
    for (int r = 0; r < 4; ++r) {
      int mm = mt * 256 + wr * 64 + i * 16 + lg * 4 + r;
      if (mm >= 6000) continue;
      #pragma unroll
      for (int j = 0; j < 4; ++j) {
        int n = nt * 128 + wn * 64 + j * 16 + lr;
        out[(size_t)mm * EDIM + n] = acc[i][j][r] + bo[n];
      }
    }
  }
}

// ---------------------------------------------------------------- launch
extern "C" void kernel_launch(void* const* d_in, const int* in_sizes, int n_in,
                              void* d_out, int out_size, void* d_ws, size_t ws_size,
                              hipStream_t stream) {
  const float* x    = (const float*)d_in[0];
  const float* mask = (const float*)d_in[1];
  const float* wq   = (const float*)d_in[2];
  const float* bq   = (const float*)d_in[3];
  const float* wk   = (const float*)d_in[4];
  const float* wv   = (const float*)d_in[5];
  const float* bv   = (const float*)d_in[6];
  const float* wo   = (const float*)d_in[7];
  const float* bo   = (const float*)d_in[8];
  float* out = (float*)d_out;
  u16* ws = (u16*)d_ws;
  u32* nzflags = (u32*)d_out;   // 1152 u32; overwritten by gemm_out later

  hipMemsetAsync(nzflags, 0, 1152 * sizeof(u32), stream);
  prep_kernel<<<2048, 256, 0, stream>>>(x, wq, wk, wv, wo, mask, ws, nzflags);
  gemm_qkv_kernel<<<720, 512, 0, stream>>>(
      ws + OFF_X, ws + OFF_W, bq, bv, ws + OFF_Q, ws + OFF_K, ws + OFF_VT);
  attn_kernel<<<dim3(12, 80), 256, 0, stream>>>(
      ws + OFF_Q, ws + OFF_K, ws + OFF_VT, mask, nzflags, ws + OFF_AO);
  gemm_out_kernel<<<240, 512, 0, stream>>>(
      ws + OFF_AO, ws + OFF_WO, bo, out);
}

// Round 10
// 240.373 us; speedup vs baseline: 1.0242x; 1.0222x over previous
//
#include <hip/hip_runtime.h>

#define T_LEN 1500
#define TP    1536
#define EDIM  1280
#define NH    20
#define HD    64
#define KDIM  1280
#define NT    20          // K tiles of 64 (1280/64)

#define LOG2E 1.4426950408889634f

// ws layout (ushort elements). AO aliases X (X dead after QKV GEMM).
#define OFF_X    ((size_t)0)
#define OFF_AO   ((size_t)0)
#define OFF_W    ((size_t)7700480)    // 6016*1280
#define OFF_WO   ((size_t)12615680)   // +3840*1280
#define OFF_Q    ((size_t)14254080)   // +1280*1280
#define OFF_K    ((size_t)22118400)   // +80*1536*64
#define OFF_VT   ((size_t)29982720)   // +80*1536*64
// total: 37847040 u16 = 75.7 MB
// mask-nonzero flags (4*12*24 u32) live in d_out[0..1152).

typedef float  f32x4  __attribute__((ext_vector_type(4)));
typedef float  f32x16 __attribute__((ext_vector_type(16)));
typedef short  s16x8  __attribute__((ext_vector_type(8)));
typedef __bf16 bf16x8 __attribute__((ext_vector_type(8)));
typedef unsigned short u16;
typedef unsigned int   u32;
typedef unsigned int u32x4 __attribute__((ext_vector_type(4)));

__device__ __forceinline__ f32x4 mfma_bf16(s16x8 a, s16x8 b, f32x4 c) {
  return __builtin_amdgcn_mfma_f32_16x16x32_bf16(
      __builtin_bit_cast(bf16x8, a), __builtin_bit_cast(bf16x8, b), c, 0, 0, 0);
}

__device__ __forceinline__ f32x16 mfma32(s16x8 a, s16x8 b, f32x16 c) {
  return __builtin_amdgcn_mfma_f32_32x32x16_bf16(
      __builtin_bit_cast(bf16x8, a), __builtin_bit_cast(bf16x8, b), c, 0, 0, 0);
}

__device__ __forceinline__ u16 f2bf(float f) {
  union { float f; unsigned int u; } a; a.f = f;
  return (u16)((a.u + 0x7fffu + ((a.u >> 16) & 1u)) >> 16);
}

__device__ __forceinline__ float fexp2(float x) {
  return __builtin_amdgcn_exp2f(x);
}

__device__ __forceinline__ void gl_lds16(const u16* g, u16* l) {
  __builtin_amdgcn_global_load_lds(
      (const __attribute__((address_space(1))) unsigned int*)(const void*)g,
      (__attribute__((address_space(3))) unsigned int*)(void*)l, 16, 0, 0);
}

// GEMM-operand pre-swizzle (rule 21, both-sides): element (row, k) of any
// GEMM A/B operand is stored at k' = (k&~63) | (((k>>3)&7 ^ (row&7))<<3) | (k&7).
// gl_lds16 stages physical granules linearly; ds_read applies the same XOR.
// Applies to: X (prep), W (prep), Wo (prep), AO (attn epilogue writes).
// K storage swizzle (attn LDS): (t,d) at d' = ((d>>3 ^ (t&7))<<3)|(d&7)
// Vt storage swizzle (attn LDS): col t' = (t&~63)|(((t>>3)&7 ^ (d&7))<<3)|(t&7)

// ---------------------------------------------------------------- prep
__global__ __launch_bounds__(256) void prep_kernel(
    const float* __restrict__ x, const float* __restrict__ wq,
    const float* __restrict__ wk, const float* __restrict__ wv,
    const float* __restrict__ wo, const float* __restrict__ mask,
    u16* __restrict__ ws, u32* __restrict__ nzflags) {
  const int S0 = 1925120;          // X vec4 count (6016*1280/4)
  const int S1 = 1228800;          // Wqkv
  const int S2 = 409600;           // Wo
  const int P1 = 46080;            // one pad region (80*36*64/4)
  const int S3 = 2250000;          // mask scan vec4 count
  const int TOT = S0 + S1 + S2 + 3 * P1 + S3;
  for (int v = blockIdx.x * 256 + threadIdx.x; v < TOT; v += gridDim.x * 256) {
    if (v < S0) {
      int i = v * 4;
      int m = i / EDIM, e = i - m * EDIM;
      int ep = (e & ~63) | (((((e >> 3) & 7) ^ (m & 7))) << 3) | (e & 7);
      ushort4 o;
      if (m < 6000) {
        float4 f = *(const float4*)(x + i);
        o = make_ushort4(f2bf(f.x), f2bf(f.y), f2bf(f.z), f2bf(f.w));
      } else {
        o = make_ushort4(0, 0, 0, 0);
      }
      *(ushort4*)(ws + OFF_X + (size_t)m * EDIM + ep) = o;
    } else if (v < S0 + S1) {
      int j = (v - S0) * 4;
      int n = j / EDIM, e = j - n * EDIM;
      const float* s = (n < 1280) ? wq + (size_t)n * EDIM + e
                     : (n < 2560) ? wk + (size_t)(n - 1280) * EDIM + e
                                  : wv + (size_t)(n - 2560) * EDIM + e;
      float4 f = *(const float4*)s;
      int ep = (e & ~63) | (((((e >> 3) & 7) ^ (n & 7))) << 3) | (e & 7);
      *(ushort4*)(ws + OFF_W + (size_t)n * EDIM + ep) =
          make_ushort4(f2bf(f.x), f2bf(f.y), f2bf(f.z), f2bf(f.w));
    } else if (v < S0 + S1 + S2) {
      int j = (v - S0 - S1) * 4;
      int n = j / EDIM, e = j - n * EDIM;
      float4 f = *(const float4*)(wo + j);
      int ep = (e & ~63) | (((((e >> 3) & 7) ^ (n & 7))) << 3) | (e & 7);
      *(ushort4*)(ws + OFF_WO + (size_t)n * EDIM + ep) =
          make_ushort4(f2bf(f.x), f2bf(f.y), f2bf(f.z), f2bf(f.w));
    } else if (v < S0 + S1 + S2 + 3 * P1) {
      int p = v - (S0 + S1 + S2);
      ushort4 z = make_ushort4(0, 0, 0, 0);
      if (p < P1) {                       // Q pad rows t in [1500,1536)
        int p4 = p * 4; int bh = p4 / 2304; int rem = p4 - bh * 2304;
        int tt = rem >> 6, d = rem & 63;
        *(ushort4*)(ws + OFF_Q + ((size_t)(bh * TP + 1500 + tt)) * HD + d) = z;
      } else if (p < 2 * P1) {            // K pad rows (zero row: swizzle-invariant)
        int p4 = (p - P1) * 4; int bh = p4 / 2304; int rem = p4 - bh * 2304;
        int tt = rem >> 6, d = rem & 63;
        *(ushort4*)(ws + OFF_K + ((size_t)(bh * TP + 1500 + tt)) * HD + d) = z;
      } else {                            // Vt pad cols s in [1500,1536), swizzled
        int p4 = (p - 2 * P1) * 4; int bh = p4 / 2304; int rem = p4 - bh * 2304;
        int d = rem / 36, ss = rem - d * 36;
        int t = 1500 + ss;
        int tphys = (t & ~63) | (((((t >> 3) & 7) ^ (d & 7))) << 3) | (t & 7);
        *(ushort4*)(ws + OFF_VT + ((size_t)(bh * HD + d)) * TP + tphys) = z;
      }
    } else {                              // mask nonzero scan
      int p = v - (S0 + S1 + S2 + 3 * P1);
      int i4 = p * 4;
      int bb = i4 / 2250000;
      int rem = i4 - bb * 2250000;
      int q = rem / 1500;
      int s = rem - q * 1500;
      float4 f = *(const float4*)(mask + (size_t)bb * 2250000 + rem);
      if (f.x != 0.f || f.y != 0.f || f.z != 0.f || f.w != 0.f)
        atomicOr(&nzflags[(bb * 12 + (q >> 7)) * 24 + (s >> 6)], 1u);
    }
  }
}

// ------------------------------------------- 256x128 pipelined mainloop
// (unchanged from round 8)
__device__ __forceinline__ void gemm_mainloop256(
    const u16* __restrict__ A, const u16* __restrict__ B,
    int mt, int nt, u16* lds, f32x4 acc[4][4]) {
  const int tid = threadIdx.x;           // 0..511
  const int lane = tid & 63, wid = tid >> 6;
  const int lg = lane >> 4, lr = lane & 15;
  const int wr = wid >> 1, wn = wid & 1;

  const u16* aB = A + (size_t)(mt * 256) * KDIM;
  const u16* bB = B + (size_t)(nt * 128) * KDIM;
  size_t aOff[4], bOff[2];
  #pragma unroll
  for (int l = 0; l < 4; ++l) {
    int gid = l * 512 + tid;            // A granule id 0..2047
    aOff[l] = (size_t)(gid >> 3) * KDIM + (gid & 7) * 8;
  }
  #pragma unroll
  for (int l = 0; l < 2; ++l) {
    int gid = l * 512 + tid;            // B granule id 0..1023
    bOff[l] = (size_t)(gid >> 3) * KDIM + (gid & 7) * 8;
  }
  const int ldsOff = tid * 8;
  int arow[4], brow[4];
  #pragma unroll
  for (int i = 0; i < 4; ++i) arow[i] = (wr * 64 + i * 16 + lr) * 64;
  #pragma unroll
  for (int j = 0; j < 4; ++j) brow[j] = (wn * 64 + j * 16 + lr) * 64;
  const int gsw0 = ((lg) ^ (lr & 7)) * 8;        // ks=0 phys granule
  const int gsw1 = ((4 + lg) ^ (lr & 7)) * 8;    // ks=1

  // prologue: stage tiles 0 (slot0) then 1 (slot1) — order matters for vmcnt
  #pragma unroll
  for (int t = 0; t < 2; ++t) {
    u16* dA = lds + t * 24576;
    u16* dB = dA + 16384;
    gl_lds16(aB + aOff[0] + t * 64, dA + ldsOff);
    gl_lds16(aB + aOff[1] + t * 64, dA + ldsOff + 4096);
    gl_lds16(bB + bOff[0] + t * 64, dB + ldsOff);
    gl_lds16(aB + aOff[2] + t * 64, dA + ldsOff + 8192);
    gl_lds16(aB + aOff[3] + t * 64, dA + ldsOff + 12288);
    gl_lds16(bB + bOff[1] + t * 64, dB + ldsOff + 4096);
  }
  // wait tile 0 only (6 of 12), then read its ks=0 fragments
  asm volatile("s_waitcnt vmcnt(6)" ::: "memory");
  __builtin_amdgcn_s_barrier();
  __builtin_amdgcn_sched_barrier(0);
  s16x8 ca[4], cb[4];
  #pragma unroll
  for (int i = 0; i < 4; ++i) ca[i] = *(const s16x8*)(lds + arow[i] + gsw0);
  #pragma unroll
  for (int j = 0; j < 4; ++j) cb[j] = *(const s16x8*)(lds + 16384 + brow[j] + gsw0);

  int s = 0;
  #pragma unroll 1
  for (int kt = 0; kt < NT; ++kt) {
    u16* cA = lds + s * 24576;
    u16* cB = cA + 16384;
    int ssl = s + 2; if (ssl >= 3) ssl -= 3;   // slot of tile kt-1 (released)
    u16* sA = lds + ssl * 24576;
    u16* sB = sA + 16384;
    const bool doStage = (kt + 2 < NT);
    // ---- P0: stage H0(kt+2) || prefetch Rnxt=(kt,ks1) || MFMA(Rcur) ----
    if (doStage) {
      gl_lds16(aB + aOff[0] + (kt + 2) * 64, sA + ldsOff);
      gl_lds16(aB + aOff[1] + (kt + 2) * 64, sA + ldsOff + 4096);
      gl_lds16(bB + bOff[0] + (kt + 2) * 64, sB + ldsOff);
    }
    s16x8 na[4], nb[4];
    #pragma unroll
    for (int i = 0; i < 4; ++i) na[i] = *(const s16x8*)(cA + arow[i] + gsw1);
    #pragma unroll
    for (int j = 0; j < 4; ++j) nb[j] = *(const s16x8*)(cB + brow[j] + gsw1);
    __builtin_amdgcn_s_setprio(1);
    #pragma unroll
    for (int i = 0; i < 4; ++i)
      #pragma unroll
      for (int j = 0; j < 4; ++j)
        acc[i][j] = mfma_bf16(ca[i], cb[j], acc[i][j]);
    __builtin_amdgcn_s_setprio(0);
    // ---- P1: stage H1(kt+2) || slot handoff || prefetch Rcur=(kt+1,ks0)
    //      || MFMA(Rnxt) ----
    if (doStage) {
      gl_lds16(aB + aOff[2] + (kt + 2) * 64, sA + ldsOff + 8192);
      gl_lds16(aB + aOff[3] + (kt + 2) * 64, sA + ldsOff + 12288);
      gl_lds16(bB + bOff[1] + (kt + 2) * 64, sB + ldsOff + 4096);
    }
    if (kt < NT - 1) {
      asm volatile("s_waitcnt lgkmcnt(0)" ::: "memory");
      if (kt < NT - 2) asm volatile("s_waitcnt vmcnt(6)" ::: "memory");
      else             asm volatile("s_waitcnt vmcnt(0)" ::: "memory");
      __builtin_amdgcn_s_barrier();
      __builtin_amdgcn_sched_barrier(0);
      int sn = s + 1; if (sn >= 3) sn = 0;
      const u16* nA = lds + sn * 24576;
      const u16* nB2 = nA + 16384;
      #pragma unroll
      for (int i = 0; i < 4; ++i) ca[i] = *(const s16x8*)(nA + arow[i] + gsw0);
      #pragma unroll
      for (int j = 0; j < 4; ++j) cb[j] = *(const s16x8*)(nB2 + brow[j] + gsw0);
    }
    __builtin_amdgcn_s_setprio(1);
    #pragma unroll
    for (int i = 0; i < 4; ++i)
      #pragma unroll
      for (int j = 0; j < 4; ++j)
        acc[i][j] = mfma_bf16(na[i], nb[j], acc[i][j]);
    __builtin_amdgcn_s_setprio(0);
    s = s + 1; if (s >= 3) s = 0;
  }
}

// ------------------------------------------------------------ QKV GEMM
__global__ __launch_bounds__(512) void gemm_qkv_kernel(
    const u16* __restrict__ X, const u16* __restrict__ W,
    const float* __restrict__ bq, const float* __restrict__ bv,
    u16* __restrict__ Qw, u16* __restrict__ Kw, u16* __restrict__ Vtw) {
  __shared__ __align__(16) u16 lds[3 * 24576];
  const int bid = blockIdx.x;
  const int xcd = bid & 7, idx = bid >> 3;
  const int mt = xcd * 3 + idx % 3;
  const int nt = idx / 3;
  f32x4 acc[4][4] = {};
  gemm_mainloop256(X, W, mt, nt, lds, acc);
  const int tid = threadIdx.x;
  const int lane = tid & 63, wid = tid >> 6;
  const int lg = lane >> 4, lr = lane & 15;
  const int wr = wid >> 1, wn = wid & 1;
  #pragma unroll
  for (int i = 0; i < 4; ++i) {
    #pragma unroll
    for (int r = 0; r < 4; ++r) {
      int mm = mt * 256 + wr * 64 + i * 16 + lg * 4 + r;
      if (mm >= 6000) continue;
      int bt = mm / 1500, tt = mm - bt * 1500;
      #pragma unroll
      for (int j = 0; j < 4; ++j) {
        int n = nt * 128 + wn * 64 + j * 16 + lr;
        float v = acc[i][j][r];
        if (n < 1280) {
          int hh = n >> 6, d = n & 63;
          Qw[((size_t)(bt * NH + hh) * TP + tt) * HD + d] =
              f2bf((v + bq[n]) * (0.125f * LOG2E));
        } else if (n < 2560) {
          int nn = n - 1280, hh = nn >> 6, d = nn & 63;
          int dp = ((((d >> 3) ^ (tt & 7))) << 3) | (d & 7);
          Kw[((size_t)(bt * NH + hh) * TP + tt) * HD + dp] = f2bf(v);
        } else {
          int nn = n - 2560, hh = nn >> 6, d = nn & 63;
          int tphys = (tt & ~63) | (((((tt >> 3) & 7) ^ (d & 7))) << 3) | (tt & 7);
          Vtw[((size_t)(bt * NH + hh) * HD + d) * TP + tphys] = f2bf(v + bv[nn]);
        }
      }
    }
  }
}

// ------------------------------------------------------------ attention
// Round-8 structure (QBLK=128, 4 waves, 256 thr — known-good numerics).
// ONLY change: 1-D grid 960 with bid%80 = head, so all 12 q-blocks of a
// head share one XCD (80 ≡ 0 mod 8) → K/V L2-resident per XCD.
__global__ __launch_bounds__(256) void attn_kernel(
    const u16* __restrict__ Qw, const u16* __restrict__ Kw,
    const u16* __restrict__ Vtw, const float* __restrict__ mask,
    const u32* __restrict__ nzflags, u16* __restrict__ AO) {
  __shared__ __align__(16) u16 Kb[2][64 * 64];
  __shared__ __align__(16) u16 Vb[2][64 * 64];
  const int bid = blockIdx.x;
  const int qt = bid / 80;                  // 0..11
  const int bhid = bid % 80;                // bid%8 == bhid%8 → same XCD/head
  const int bb = bhid / NH, hh = bhid % NH;
  const int tid = threadIdx.x;
  const int w = tid >> 6;
  const int lane = tid & 63;
  const int lq = lane & 31;
  const int hi = lane >> 5;
  const int q0 = qt * 128 + w * 32;
  const int qrow = q0 + lq;
  const int qm = qrow < (T_LEN - 1) ? qrow : (T_LEN - 1);
  const u16* Qp = Qw + (size_t)bhid * TP * HD;
  const u16* Kp = Kw + (size_t)bhid * TP * HD;
  const u16* Vp = Vtw + (size_t)bhid * HD * TP;
  const float* mp = mask + (size_t)bb * T_LEN * T_LEN + (size_t)qm * T_LEN;
  const u32* nzp = nzflags + (bb * 12 + qt) * 24;

  s16x8 qf[4];
  #pragma unroll
  for (int c = 0; c < 4; ++c)
    qf[c] = *(const s16x8*)(Qp + (size_t)qrow * HD + c * 16 + hi * 8);

  f32x16 O0 = {}, O1 = {};
  float m = -3e38f, l = 0.f;

  {
    gl_lds16(Kp + tid * 8,                 Kb[0] + tid * 8);
    gl_lds16(Kp + 2048 + tid * 8,          Kb[0] + 2048 + tid * 8);
    int r = tid >> 3, g = tid & 7;
    gl_lds16(Vp + (size_t)r * TP + g * 8,          Vb[0] + tid * 8);
    gl_lds16(Vp + (size_t)(r + 32) * TP + g * 8,   Vb[0] + 2048 + tid * 8);
  }
  __syncthreads();

  int buf = 0;
  #pragma unroll 1
  for (int st = 0; st < 24; ++st) {
    const int s0 = st * 64;
    if (st < 23) {
      const int sn = s0 + 64;
      gl_lds16(Kp + (size_t)sn * HD + tid * 8,        Kb[buf ^ 1] + tid * 8);
      gl_lds16(Kp + (size_t)sn * HD + 2048 + tid * 8, Kb[buf ^ 1] + 2048 + tid * 8);
      int r = tid >> 3, g = tid & 7;
      gl_lds16(Vp + (size_t)r * TP + sn + g * 8,        Vb[buf ^ 1] + tid * 8);
      gl_lds16(Vp + (size_t)(r + 32) * TP + sn + g * 8, Vb[buf ^ 1] + 2048 + tid * 8);
    }
    const bool has_mask = nzp[st] != 0u;
    const u16* kb = Kb[buf];
    f32x16 S0a = {}, S1a = {};
    #pragma unroll
    for (int c = 0; c < 4; ++c) {
      int gc = 2 * c + hi;
      int gs = (gc ^ (lq & 7)) << 3;
      s16x8 k0 = *(const s16x8*)(kb + lq * 64 + gs);
      s16x8 k1 = *(const s16x8*)(kb + (32 + lq) * 64 + gs);
      S0a = mfma32(k0, qf[c], S0a);
      S1a = mfma32(k1, qf[c], S1a);
    }
    float p[32];
    #pragma unroll
    for (int r = 0; r < 16; ++r) { p[r] = S0a[r]; p[16 + r] = S1a[r]; }
    if (has_mask) {
      f32x4 mk[2][4];
      #pragma unroll
      for (int sh = 0; sh < 2; ++sh)
        #pragma unroll
        for (int g = 0; g < 4; ++g) {
          int sb = s0 + sh * 32 + 8 * g + 4 * hi;
          if (sb > T_LEN - 4) sb = T_LEN - 4;
          mk[sh][g] = *(const f32x4*)(mp + sb);
        }
      #pragma unroll
      for (int r = 0; r < 16; ++r) {
        p[r]      = fmaf(mk[0][r >> 2][r & 3], LOG2E, p[r]);
        p[16 + r] = fmaf(mk[1][r >> 2][r & 3], LOG2E, p[16 + r]);
      }
    }
    if (st == 23) {
      if (hi) { p[12] = p[13] = p[14] = p[15] = -1e30f; }
      #pragma unroll
      for (int r = 16; r < 32; ++r) p[r] = -1e30f;
    }
    float t1[16];
    #pragma unroll
    for (int r = 0; r < 16; ++r) t1[r] = fmaxf(p[r], p[r + 16]);
    #pragma unroll
    for (int r = 0; r < 8; ++r) t1[r] = fmaxf(t1[r], t1[r + 8]);
    float mx = fmaxf(fmaxf(fmaxf(t1[0], t1[1]), fmaxf(t1[2], t1[3])),
                     fmaxf(fmaxf(t1[4], t1[5]), fmaxf(t1[6], t1[7])));
    mx = fmaxf(mx, __shfl_xor(mx, 32));
    if (!__all(mx <= m + 8.f)) {
      float mn = fmaxf(m, mx);
      float sc = fexp2(m - mn);
      O0 *= sc; O1 *= sc; l *= sc;
      m = mn;
    }
    #pragma unroll
    for (int r = 0; r < 32; ++r) p[r] = fexp2(p[r] - m);
    float s1[16];
    #pragma unroll
    for (int r = 0; r < 16; ++r) s1[r] = p[r] + p[r + 16];
    #pragma unroll
    for (int r = 0; r < 8; ++r) s1[r] += s1[r + 8];
    #pragma unroll
    for (int r = 0; r < 4; ++r) s1[r] += s1[r + 4];
    float rs = (s1[0] + s1[1]) + (s1[2] + s1[3]);
    rs += __shfl_xor(rs, 32);
    l += rs;
    const u16* vb = Vb[buf];
    #pragma unroll
    for (int sh = 0; sh < 2; ++sh) {
      u32 pk[8];
      #pragma unroll
      for (int j = 0; j < 8; ++j)
        asm("v_cvt_pk_bf16_f32 %0, %1, %2"
            : "=v"(pk[j]) : "v"(p[sh * 16 + 2 * j]), "v"(p[sh * 16 + 2 * j + 1]));
      asm("v_permlane32_swap_b32 %0, %1" : "+v"(pk[0]), "+v"(pk[2]));
      asm("v_permlane32_swap_b32 %0, %1" : "+v"(pk[1]), "+v"(pk[3]));
      asm("v_permlane32_swap_b32 %0, %1" : "+v"(pk[4]), "+v"(pk[6]));
      asm("v_permlane32_swap_b32 %0, %1" : "+v"(pk[5]), "+v"(pk[7]));
      u32x4 ta = {pk[0], pk[1], pk[2], pk[3]};
      u32x4 tb = {pk[4], pk[5], pk[6], pk[7]};
      s16x8 pfa = __builtin_bit_cast(s16x8, ta);
      s16x8 pfb = __builtin_bit_cast(s16x8, tb);
      int ga = sh * 4 + hi, gb = sh * 4 + 2 + hi;
      {
        int d = lq;
        s16x8 va = *(const s16x8*)(vb + d * 64 + ((ga ^ (d & 7)) << 3));
        s16x8 vc = *(const s16x8*)(vb + d * 64 + ((gb ^ (d & 7)) << 3));
        O0 = mfma32(va, pfa, O0);
        O0 = mfma32(vc, pfb, O0);
      }
      {
        int d = 32 + lq;
        s16x8 va = *(const s16x8*)(vb + d * 64 + ((ga ^ (d & 7)) << 3));
        s16x8 vc = *(const s16x8*)(vb + d * 64 + ((gb ^ (d & 7)) << 3));
        O1 = mfma32(va, pfa, O1);
        O1 = mfma32(vc, pfb, O1);
      }
    }
    __syncthreads();
    buf ^= 1;
  }

  if (qrow < T_LEN) {
    float inv = 1.f / l;
    int arow = bb * T_LEN + qrow;
    int key = arow & 7;                  // AO pre-swizzle for gemm_out (rule 21)
    size_t base = (size_t)arow * EDIM + hh * 64;
    #pragma unroll
    for (int g = 0; g < 4; ++g) {
      ushort4 o0, o1;
      o0.x = f2bf(O0[4 * g + 0] * inv); o0.y = f2bf(O0[4 * g + 1] * inv);
      o0.z = f2bf(O0[4 * g + 2] * inv); o0.w = f2bf(O0[4 * g + 3] * inv);
      o1.x = f2bf(O1[4 * g + 0] * inv); o1.y = f2bf(O1[4 * g + 1] * inv);
      o1.z = f2bf(O1[4 * g + 2] * inv); o1.w = f2bf(O1[4 * g + 3] * inv);
      *(ushort4*)(AO + base + ((g ^ key) << 3) + 4 * hi)       = o0;
      *(ushort4*)(AO + base + (((4 + g) ^ key) << 3) + 4 * hi) = o1;
    }
  }
}

// --------------------------------------------------------- output GEMM
__global__ __launch_bounds__(512) void gemm_out_kernel(
    const u16* __restrict__ AOb, const u16* __restrict__ Wob,
    const float* __restrict__ bo, float* __restrict__ out) {
  __shared__ __align__(16) u16 lds[3 * 24576];
  const int bid = blockIdx.x;
  const int xcd = bid & 7, idx = bid >> 3;
  const int mt = xcd * 3 + idx % 3;
  const int nt = idx / 3;
  f32x4 acc[4][4] = {};
  gemm_mainloop256(AOb, Wob, mt, nt, lds, acc);
  const int tid = threadIdx.x;
  const int lane = tid & 63, wid = tid >> 6;
  const int lg = lane >> 4, lr = lane & 15;
  const int wr = wid >> 1, wn = wid & 1;
  #pragma unroll
  for (int i = 0; i < 4; ++i) {
    #pragma unroll
    for (int r = 0; r < 4; ++r) {
      int mm = mt * 256 + wr * 64 + i * 16 + lg * 4 + r;
      if (mm >= 6000) continue;
      #pragma unroll
      for (int j = 0; j < 4; ++j) {
        int n = nt * 128 + wn * 64 + j * 16 + lr;
        out[(size_t)mm * EDIM + n] = acc[i][j][r] + bo[n];
      }
    }
  }
}

// ---------------------------------------------------------------- launch
extern "C" void kernel_launch(void* const* d_in, const int* in_sizes, int n_in,
                              void* d_out, int out_size, void* d_ws, size_t ws_size,
                              hipStream_t stream) {
  const float* x    = (const float*)d_in[0];
  const float* mask = (const float*)d_in[1];
  const float* wq   = (const float*)d_in[2];
  const float* bq   = (const float*)d_in[3];
  const float* wk   = (const float*)d_in[4];
  const float* wv   = (const float*)d_in[5];
  const float* bv   = (const float*)d_in[6];
  const float* wo   = (const float*)d_in[7];
  const float* bo   = (const float*)d_in[8];
  float* out = (float*)d_out;
  u16* ws = (u16*)d_ws;
  u32* nzflags = (u32*)d_out;   // 1152 u32; overwritten by gemm_out later

  hipMemsetAsync(nzflags, 0, 1152 * sizeof(u32), stream);
  prep_kernel<<<2048, 256, 0, stream>>>(x, wq, wk, wv, wo, mask, ws, nzflags);
  gemm_qkv_kernel<<<720, 512, 0, stream>>>(
      ws + OFF_X, ws + OFF_W, bq, bv, ws + OFF_Q, ws + OFF_K, ws + OFF_VT);
  attn_kernel<<<960, 256, 0, stream>>>(
      ws + OFF_Q, ws + OFF_K, ws + OFF_VT, mask, nzflags, ws + OFF_AO);
  gemm_out_kernel<<<240, 512, 0, stream>>>(
      ws + OFF_AO, ws + OFF_WO, bo, out);
}